// Round 1
// 195.086 us; speedup vs baseline: 1.0219x; 1.0219x over previous
//
#include <hip/hip_runtime.h>

// CTC forward loss. T=1024, B=128, C=256, S=64, L=129.
// 3 waves per block (one block per batch element):
//   waves 1-2 (producers): gather lp[t][b][tgt_lane] + lp[t][b][0], exp()
//     both, stage {eml, ebl} float2 into a 2-chunk LDS ring. R9: producer is
//     pipelined ACROSS the chunk barrier: all 64 loads of chunk kc+2 (4 named
//     8-row register sets = 64 floats/lane) are issued while the consumer
//     processes chunk kc, and drained into LDS during chunk kc+1. The ~900cy
//     HBM latency gets a full chunk window (~1700cy) to complete, so producer
//     in-loop cost drops to ~700cy/chunk (was ~2400 with the in-chunk 8-row
//     ping-pong of R8) and stays hidden under the consumer.
//   wave 0 (consumer): alpha recurrence in SCALED LINEAR FP32 (R9; was f64):
//     p_s = exp(alpha_s) * 2^es (es = wave-uniform int exponent).
//     f32 halves VALU issue cost vs f64 (2 vs 4 cyc/op), kills the two
//     f32->f64 converts per step, and makes the lane-shift a SINGLE dpp mov.
//     Lane i holds p[2i] ("pa"), p[2i+1] ("pb"); lane 63 also p[128] ("pc").
//     ds_reads pipelined with rotating float2 regs (distance 4).
//     Rescale every 8 steps (f32 window: worst-case 8-step decay 2^-104 >
//     2^-126 min-normal; states >e^-80 below the max flush harmlessly).
//   Rescale: int-max DPP over f32 bit patterns (positive floats order as
//   ints), readlane, exact power-of-2 ldexpf => value-preserving.

#define NEGV (-1e30f)
#define NEGH (-5e29f)

constexpr int T_  = 1024;
constexpr int C_  = 256;
constexpr int CH  = 64;        // rows per chunk
constexpr int NCH = T_ / CH;   // 16 chunks covering t = 1 .. 1024

__device__ __forceinline__ float lse2f(float x, float y) {
    float m = fmaxf(x, y);
    float s = __expf(x - m) + __expf(y - m);
    float r = m + __logf(s);
    return (m > NEGH) ? r : NEGV;
}

// float from lane i-1; lane 0 gets 0.0f. One b32 DPP wave_shr:1 (pure VALU).
__device__ __forceinline__ float fshr1(float x) {
    int i = __float_as_int(x);
    int p = __builtin_amdgcn_update_dpp(0, i, 0x138, 0xf, 0xf, false);
    return __int_as_float(p);
}

// one step of a DPP int-max reduction; old = x is identity under max
template <int CTRL>
__device__ __forceinline__ int dpp_imaxstep(int x) {
    int r = __builtin_amdgcn_update_dpp(x, x, CTRL, 0xf, 0xf, false);
    return max(x, r);
}

// ---- producer register-set macros (named regs; R6: arrays are NOT promoted)
#define PDECL(S) float S##g0,S##g1,S##g2,S##g3,S##g4,S##g5,S##g6,S##g7, \
                       S##l0,S##l1,S##l2,S##l3,S##l4,S##l5,S##l6,S##l7
#define PLOAD1(S,J,TB) { int t_ = (TB) + J; t_ = t_ > 1023 ? 1023 : t_;      \
    const float* rp_ = rowb + (size_t)t_ * BC;                               \
    S##g##J = rp_[my_tgt]; S##l##J = rp_[0]; }
#define PLOAD(S,TB) PLOAD1(S,0,TB) PLOAD1(S,1,TB) PLOAD1(S,2,TB)             \
                    PLOAD1(S,3,TB) PLOAD1(S,4,TB) PLOAD1(S,5,TB)             \
                    PLOAD1(S,6,TB) PLOAD1(S,7,TB)
#define PSTORE1(S,J,RB,BUFP) BUFP[((RB) + J) * 64 + lane] =                  \
    make_float2(__expf(S##g##J), __expf(S##l##J));
#define PSTORE(S,RB,BUFP) PSTORE1(S,0,RB,BUFP) PSTORE1(S,1,RB,BUFP)          \
                          PSTORE1(S,2,RB,BUFP) PSTORE1(S,3,RB,BUFP)          \
                          PSTORE1(S,4,RB,BUFP) PSTORE1(S,5,RB,BUFP)          \
                          PSTORE1(S,6,RB,BUFP) PSTORE1(S,7,RB,BUFP)
// whole 32-row chunk slice in registers: 64 floats/lane in flight
#define LOADCHUNK(T0) PLOAD(A,(T0)) PLOAD(Bx,(T0)+8)                         \
                      PLOAD(Cx,(T0)+16) PLOAD(Dx,(T0)+24)
#define STORECHUNK(RB,BUFP) PSTORE(A,(RB),BUFP) PSTORE(Bx,(RB)+8,BUFP)       \
                            PSTORE(Cx,(RB)+16,BUFP) PSTORE(Dx,(RB)+24,BUFP)

__global__ __launch_bounds__(192) void ctc_alpha_kernel(
    const float* __restrict__ lp,      // (T, B, C) log-probs
    const int* __restrict__ targets,   // (B*S,)
    const int* __restrict__ in_len,    // (B,)
    const int* __restrict__ tgt_len,   // (B,)
    float* __restrict__ partial,       // (B,) per-batch loss/tl
    int B, int S)
{
    __shared__ float2 stage[2][CH * 64];   // 64 KiB emit-pair ring
    __shared__ float sh[132];

    const int b    = blockIdx.x;
    const int tid  = threadIdx.x;
    const int wave = tid >> 6;
    const int lane = tid & 63;
    const int BC   = B * C_;
    const float* rowb = lp + (size_t)b * C_;   // row at time t: rowb + t*BC

    int my_tgt = (lane < S) ? targets[b * S + lane] : 0;
    int prev_tgt = __shfl_up(my_tgt, 1);
    const bool skip = (lane > 0) && (my_tgt != prev_tgt) && (my_tgt != 0);
    const float skipf = skip ? 1.f : 0.f;
    const int ilen = in_len[b];

    // f32 linear-domain state: p = exp(alpha) * 2^es
    float pa = 0.f, pb = 0.f, pc = 0.f;
    int es = 0;

    PDECL(A); PDECL(Bx); PDECL(Cx); PDECL(Dx);   // producer in-flight regs
    const int r0 = (wave - 1) * 32;              // producer row base (wave0: unused)

    if (wave >= 1) {
        // chunk 0: load + drain now; chunk 1: loads in flight across barrier
        LOADCHUNK(1 + r0);
        { float2* bp = &stage[0][0]; STORECHUNK(r0, bp); }
        LOADCHUNK(1 + CH + r0);
    } else if (lane == 0) {
        pa = __expf(rowb[0]);        // alpha0[0]
        pb = __expf(rowb[my_tgt]);   // alpha0[1]
    }
    __syncthreads();   // chunk 0 staged

#define STEP(cur) {                                                          \
        float eml = (cur).x;                                                 \
        float ebl = (cur).y;                                                 \
        float pprev = fshr1(pb);             /* p[2i-1] */                   \
        float t0s = pa + pb;                 /* indep of dpp */              \
        float nb = fmaf(skipf, pprev, t0s) * eml;   /* state 2i+1 */         \
        float na = (pa + pprev) * ebl;       /* state 2i   */                \
        float nc = (pc + pb) * ebl;          /* state 128  */                \
        pa = na; pb = nb; pc = nc; }

#define RESCALE() {                                                          \
        int h = __float_as_int(fmaxf(fmaxf(pa, pb), pc));                    \
        h = dpp_imaxstep<0x111>(h);   /* row_shr:1   */                      \
        h = dpp_imaxstep<0x112>(h);   /* row_shr:2   */                      \
        h = dpp_imaxstep<0x114>(h);   /* row_shr:4   */                      \
        h = dpp_imaxstep<0x118>(h);   /* row_shr:8   */                      \
        h = dpp_imaxstep<0x142>(h);   /* row_bcast:15*/                      \
        h = dpp_imaxstep<0x143>(h);   /* row_bcast:31*/                      \
        int hm = __builtin_amdgcn_readlane(h, 63);                           \
        int e = ((hm >> 23) & 0xff) - 127;                                   \
        pa = ldexpf(pa, -e); pb = ldexpf(pb, -e); pc = ldexpf(pc, -e);       \
        es += e; }

    for (int kc = 0; kc < NCH; ++kc) {
        if (wave >= 1) {
            if (kc + 1 < NCH) {     // drain loads issued one chunk ago
                float2* bp = &stage[(kc + 1) & 1][0];
                STORECHUNK(r0, bp);
            }
            if (kc + 2 < NCH) {     // issue next chunk's loads; full window
                LOADCHUNK(1 + (kc + 2) * CH + r0);   // to complete before use
            }
        } else {
            const int t0 = 1 + kc * CH;
            const float2* sb = &stage[kc & 1][lane];   // row stride 64
            if (t0 + CH <= ilen) {
                // fast path: every step active -> no per-step branch
                float2 f0 = sb[0 * 64];
                float2 f1 = sb[1 * 64];
                float2 f2 = sb[2 * 64];
                float2 f3 = sb[3 * 64];
#pragma unroll
                for (int r = 0; r < CH; ++r) {
                    float2 cur = f0;
                    f0 = f1; f1 = f2; f2 = f3;
                    if (r + 4 < CH) f3 = sb[(r + 4) * 64];
                    STEP(cur);
                    if ((r & 7) == 7) RESCALE();
                }
            } else if (t0 < ilen) {
                // boundary chunk: wave-uniform per-step mask
                float2 f0 = sb[0 * 64];
                float2 f1 = sb[1 * 64];
                float2 f2 = sb[2 * 64];
                float2 f3 = sb[3 * 64];
#pragma unroll
                for (int r = 0; r < CH; ++r) {
                    float2 cur = f0;
                    f0 = f1; f1 = f2; f2 = f3;
                    if (r + 4 < CH) f3 = sb[(r + 4) * 64];
                    if (t0 + r < ilen) {
                        STEP(cur);
                        if ((r & 7) == 7) RESCALE();
                    }
                }
            }
        }
        __syncthreads();   // chunk boundary: stage drained, buffers swap
    }

    // Epilogue: p (f32) + es -> log-domain float, lane 0 computes the loss
    if (wave == 0) {
        const double lses = (double)es * 0.6931471805599453;
        auto logp = [&](float p) -> float {
            if (p == 0.f) return NEGV;
            float q = p * 33554432.0f;          // *2^25: normalize denormals
            if (q == 0.f) return NEGV;          // (covers FTZ mode too)
            int h = __float_as_int(q);
            int E = ((h >> 23) & 0xff) - 127 - 25;
            float m = __int_as_float((h & 0x807fffff) | (127 << 23)); // [1,2)
            return (float)(__logf(m) + ((double)E * 0.6931471805599453 + lses));
        };
        sh[2 * lane]     = logp(pa);
        sh[2 * lane + 1] = logp(pb);
        if (lane == 63) sh[128] = logp(pc);
    }
    __syncthreads();
    if (tid == 0) {
        int tl = tgt_len[b];
        int hi2 = 2 * tl;
        float ll = lse2f(sh[hi2], sh[hi2 - 1]);
        float loss = (ll > NEGH) ? -ll : 0.f;
        partial[b] = loss / (float)tl;
    }
}

__global__ __launch_bounds__(128) void ctc_reduce_kernel(
    const float* __restrict__ partial, float* __restrict__ out, int B)
{
    float v = 0.f;
    for (int j = threadIdx.x; j < B; j += 128) v += partial[j];
#pragma unroll
    for (int off = 32; off > 0; off >>= 1)
        v += __shfl_down(v, off);       // 64-lane wave reduce
    __shared__ float ws[2];
    if ((threadIdx.x & 63) == 0) ws[threadIdx.x >> 6] = v;
    __syncthreads();
    if (threadIdx.x == 0) out[0] = (ws[0] + ws[1]) / (float)B;
}

extern "C" void kernel_launch(void* const* d_in, const int* in_sizes, int n_in,
                              void* d_out, int out_size, void* d_ws, size_t ws_size,
                              hipStream_t stream)
{
    const float* lp      = (const float*)d_in[0];  // (T,B,C) float32
    const int*   targets = (const int*)d_in[1];    // (B*S,)  int32
    const int*   il      = (const int*)d_in[2];    // (B,)
    const int*   tl      = (const int*)d_in[3];    // (B,)
    const int B = in_sizes[2];
    const int S = in_sizes[1] / B;

    float* partial = (float*)d_ws;     // B floats of scratch

    ctc_alpha_kernel<<<B, 192, 0, stream>>>(lp, targets, il, tl, partial, B, S);
    ctc_reduce_kernel<<<1, 128, 0, stream>>>(partial, (float*)d_out, B);
}